// Round 8
// baseline (2529.936 us; speedup 1.0000x reference)
//
#include <hip/hip_runtime.h>
#include <hip/hip_bf16.h>
#include <math.h>

typedef unsigned short u16;
typedef __bf16 bf16x8 __attribute__((ext_vector_type(8)));
typedef float floatx4 __attribute__((ext_vector_type(4)));

#define LORA_SCALING 2.0f   // alpha 32 / rank 16

// Frag-major layout for all GEMM operands (1 KB per 16x32 fragment):
// frag idx = (row/16)*(K/32) + (k/32); lane l holds row = 16*(row/16)+(l&15),
// k = 32*(k/32) + (l>>4)*8 .. +7, at frag*512 + l*8 (u16).
// DMA of one frag = linear 1 KB; ds_read at frag_base + lane*16 = MFMA operand.

// ---------- helpers ----------
__device__ __forceinline__ u16 f2bf(float f) {
  unsigned u = __float_as_uint(f);
  u += 0x7fffu + ((u >> 16) & 1u);   // round-to-nearest-even
  return (u16)(u >> 16);
}
__device__ __forceinline__ float bflo(unsigned u) { return __uint_as_float(u << 16); }
__device__ __forceinline__ float bfhi(unsigned u) { return __uint_as_float(u & 0xffff0000u); }

// ---------- zero amax slots (ws poisoned 0xAA each launch) ----------
__global__ void zero_kernel(unsigned* amax) {
  if (threadIdx.x < 2) amax[threadIdx.x] = 0u;
}

// ---------- fused absmax of both weight tensors ----------
__global__ void absmax2_kernel(const float* __restrict__ wa, const float* __restrict__ wb,
                               long long n4, unsigned* __restrict__ out) {
  int which = blockIdx.x & 1;
  const float* w = which ? wb : wa;
  long long i = (long long)(blockIdx.x >> 1) * blockDim.x + threadIdx.x;
  long long stride = (long long)(gridDim.x >> 1) * blockDim.x;
  float m = 0.f;
  for (; i < n4; i += stride) {
    float4 v = ((const float4*)w)[i];
    m = fmaxf(m, fmaxf(fmaxf(fabsf(v.x), fabsf(v.y)), fmaxf(fabsf(v.z), fabsf(v.w))));
  }
#pragma unroll
  for (int o = 32; o > 0; o >>= 1) m = fmaxf(m, __shfl_xor(m, o, 64));
  __shared__ float sm[4];
  int lane = threadIdx.x & 63, wv = threadIdx.x >> 6;
  if (lane == 0) sm[wv] = m;
  __syncthreads();
  if (threadIdx.x == 0) {
    float mm = fmaxf(fmaxf(sm[0], sm[1]), fmaxf(sm[2], sm[3]));
    atomicMax(out + which, __float_as_uint(mm));   // nonneg: uint order == float order
  }
}

// ---------- packing, dst-major: coalesced 16B writes, gathered 32B reads ----------
__device__ __forceinline__ void pack_q(const float* __restrict__ w, u16* __restrict__ dst,
                                       long long d, int nkc, int kc3, float inv, float scale) {
  int l = (int)(d & 63);
  long long frag = d >> 6;
  long long m = (frag / nkc) * 16 + (l & 15);
  long long k8 = (frag % nkc) * 4 + (l >> 4);
  const float4* s = (const float4*)(w + ((m << kc3) + k8) * 8);
  float4 a = s[0], b = s[1];
  union { u16 h[8]; uint4 v; } o;
  o.h[0] = f2bf(fminf(fmaxf(rintf(a.x * inv), -128.f), 127.f) * scale);
  o.h[1] = f2bf(fminf(fmaxf(rintf(a.y * inv), -128.f), 127.f) * scale);
  o.h[2] = f2bf(fminf(fmaxf(rintf(a.z * inv), -128.f), 127.f) * scale);
  o.h[3] = f2bf(fminf(fmaxf(rintf(a.w * inv), -128.f), 127.f) * scale);
  o.h[4] = f2bf(fminf(fmaxf(rintf(b.x * inv), -128.f), 127.f) * scale);
  o.h[5] = f2bf(fminf(fmaxf(rintf(b.y * inv), -128.f), 127.f) * scale);
  o.h[6] = f2bf(fminf(fmaxf(rintf(b.z * inv), -128.f), 127.f) * scale);
  o.h[7] = f2bf(fminf(fmaxf(rintf(b.w * inv), -128.f), 127.f) * scale);
  ((uint4*)dst)[d] = o.v;
}
__device__ __forceinline__ void pack_c(const float* __restrict__ x, u16* __restrict__ dst,
                                       long long d, int nkc, int kc3) {
  int l = (int)(d & 63);
  long long frag = d >> 6;
  long long m = (frag / nkc) * 16 + (l & 15);
  long long k8 = (frag % nkc) * 4 + (l >> 4);
  const float4* s = (const float4*)(x + ((m << kc3) + k8) * 8);
  float4 a = s[0], b = s[1];
  union { u16 h[8]; uint4 v; } o;
  o.h[0] = f2bf(a.x); o.h[1] = f2bf(a.y); o.h[2] = f2bf(a.z); o.h[3] = f2bf(a.w);
  o.h[4] = f2bf(b.x); o.h[5] = f2bf(b.y); o.h[6] = f2bf(b.z); o.h[7] = f2bf(b.w);
  ((uint4*)dst)[d] = o.v;
}

__global__ void pack_all_kernel(const float* __restrict__ wfc, const float* __restrict__ wpr,
                                const float* __restrict__ x, const unsigned* __restrict__ amax,
                                u16* __restrict__ qfc, u16* __restrict__ qpr, u16* __restrict__ xb,
                                long long nfc, long long npr, long long nx, int kfc, int kpr, int kx) {
  float am0 = __uint_as_float(amax[0]);
  float am1 = __uint_as_float(amax[1]);
  float sc0 = am0 * (1.0f / 127.0f), in0 = 127.0f / am0;
  float sc1 = am1 * (1.0f / 127.0f), in1 = 127.0f / am1;
  long long i = (long long)blockIdx.x * blockDim.x + threadIdx.x;
  long long stride = (long long)gridDim.x * blockDim.x;
  long long tot = nfc + npr + nx;
  for (; i < tot; i += stride) {
    if (i < nfc)            pack_q(wfc, qfc, i, 1 << (kfc - 2), kfc, in0, sc0);
    else if (i < nfc + npr) pack_q(wpr, qpr, i - nfc, 1 << (kpr - 2), kpr, in1, sc1);
    else                    pack_c(x, xb, i - nfc - npr, 1 << (kx - 2), kx);
  }
}

// ---------- LoRA t = X(packed bf16) @ A^T(fp32): one wave per row, X read once ----------
__global__ void lora_t_kernel(const u16* __restrict__ X, const float* __restrict__ A,
                              float* __restrict__ T, int K) {
  int wv = threadIdx.x >> 6, lane = threadIdx.x & 63;
  long long row = (long long)blockIdx.x * 4 + wv;
  int nk = K >> 5;
  const u16* xp = X + ((row >> 4) * (long long)nk) * 512 + (row & 15) * 8;
  float acc[16];
#pragma unroll
  for (int r = 0; r < 16; ++r) acc[r] = 0.f;
  int nseg = K >> 3;
  for (int seg = lane; seg < nseg; seg += 64) {
    uint4 xv = *(const uint4*)(xp + (seg >> 2) * 512 + (seg & 3) * 128);
    float x0 = bflo(xv.x), x1 = bfhi(xv.x), x2 = bflo(xv.y), x3 = bfhi(xv.y);
    float x4 = bflo(xv.z), x5 = bfhi(xv.z), x6 = bflo(xv.w), x7 = bfhi(xv.w);
    int k = seg * 8;
#pragma unroll
    for (int r = 0; r < 16; ++r) {
      const float4* ar = (const float4*)(A + (long long)r * K + k);
      float4 a0 = ar[0], a1 = ar[1];
      acc[r] += x0 * a0.x + x1 * a0.y + x2 * a0.z + x3 * a0.w
              + x4 * a1.x + x5 * a1.y + x6 * a1.z + x7 * a1.w;
    }
  }
#pragma unroll
  for (int r = 0; r < 16; ++r) {
    float v = acc[r];
#pragma unroll
    for (int o = 32; o > 0; o >>= 1) v += __shfl_xor(v, o, 64);
    if (lane == r) T[row * 16 + r] = v;
  }
}

// ---------- main GEMM: LDS-staged (DMA), occupancy-first ----------
// Block tile (MT*32) x 128, BK=32, 256 threads = 4 waves (2x2);
// wave tile (MT*16) x 64 = MT x 4 frags of 16x16x32 bf16.
// __launch_bounds__(256,4): force VGPR+AGPR <= 128 -> 4 blocks/CU = 16 waves
// (empirical law rounds 1-7: ~1.4 B/cyc per resident wave, all structures).
template<int MT, int DO_GELU>
__global__ __launch_bounds__(256, 4)
void gemm_qlora_kernel(const u16* __restrict__ Apk, const u16* __restrict__ Bpk,
                       const float* __restrict__ bias, const float* __restrict__ T,
                       const float* __restrict__ Bl, void* __restrict__ outp,
                       int M, int N, int K) {
  constexpr int AF = 2 * MT;            // A frag-rows per block
  constexpr int APW = AF / 4;           // A frags staged per wave (2 or 1)
  __shared__ u16 sA[AF * 512];
  __shared__ u16 sB[8 * 512];
  const int tid = threadIdx.x;
  const int wave = tid >> 6, lane = tid & 63;
  const int quad = lane >> 4, m16 = lane & 15;

  // XCD partition: id&7 = XCD, bm-local fastest (A strip L2-resident)
  const int bmt = M / (MT * 32);
  const int per = bmt >> 3;
  int xcd = blockIdx.x & 7, t = blockIdx.x >> 3;
  int bm = xcd * per + (t & (per - 1));
  int bn = t / per;

  const int wm = (wave >> 1) * (MT * 16), wn = (wave & 1) * 64;
  const int nk = K >> 5;

  // staging sources (per-lane addr = frag base + lane*16B) and LDS dests (wave-uniform)
  const u16* gA[APW];
  u16* lA[APW];
#pragma unroll
  for (int i = 0; i < APW; ++i) {
    gA[i] = Apk + ((size_t)(bm * AF + wave * APW + i) * nk) * 512 + lane * 8;
    lA[i] = sA + (wave * APW + i) * 512;
  }
  const u16* gB[2];
  u16* lB[2];
#pragma unroll
  for (int i = 0; i < 2; ++i) {
    gB[i] = Bpk + ((size_t)(bn * 8 + wave * 2 + i) * nk) * 512 + lane * 8;
    lB[i] = sB + (wave * 2 + i) * 512;
  }

  const u16* rA = sA + (wave >> 1) * (MT * 512) + lane * 8;
  const u16* rB = sB + (wave & 1) * (4 * 512) + lane * 8;

  floatx4 acc[MT][4] = {};

#pragma unroll 1
  for (int kt = 0; kt < nk; ++kt) {
    size_t o = (size_t)kt * 512;
#pragma unroll
    for (int i = 0; i < APW; ++i)
      __builtin_amdgcn_global_load_lds((const __attribute__((address_space(1))) void*)(gA[i] + o),
                                       (__attribute__((address_space(3))) void*)lA[i], 16, 0, 0);
#pragma unroll
    for (int i = 0; i < 2; ++i)
      __builtin_amdgcn_global_load_lds((const __attribute__((address_space(1))) void*)(gB[i] + o),
                                       (__attribute__((address_space(3))) void*)lB[i], 16, 0, 0);
    __syncthreads();

    bf16x8 av[MT], bv[4];
#pragma unroll
    for (int mt = 0; mt < MT; ++mt) av[mt] = *(const bf16x8*)(rA + mt * 512);
#pragma unroll
    for (int nt = 0; nt < 4; ++nt) bv[nt] = *(const bf16x8*)(rB + nt * 512);
#pragma unroll
    for (int mt = 0; mt < MT; ++mt)
#pragma unroll
      for (int nt = 0; nt < 4; ++nt)
        acc[mt][nt] = __builtin_amdgcn_mfma_f32_16x16x32_bf16(av[mt], bv[nt], acc[mt][nt], 0, 0, 0);
    __syncthreads();
  }

  // epilogue: C/D layout row=(lane>>4)*4+reg, col=lane&15
  const float* Trow = T + (size_t)bm * (MT * 32) * 16;
  const float* Blrow = Bl + (size_t)bn * 128 * 16;
#pragma unroll 1
  for (int mt = 0; mt < MT; ++mt) {
#pragma unroll 1
    for (int r = 0; r < 4; ++r) {
      int ml = wm + mt * 16 + quad * 4 + r;
      size_t gm = (size_t)bm * (MT * 32) + ml;
      const float4* tv = (const float4*)(Trow + (size_t)ml * 16);
      float4 ta = tv[0], tb = tv[1], tc = tv[2], td = tv[3];
#pragma unroll
      for (int nt = 0; nt < 4; ++nt) {
        int nl = wn + nt * 16 + m16;
        size_t gn = (size_t)bn * 128 + nl;
        const float4* bv4 = (const float4*)(Blrow + (size_t)nl * 16);
        float4 ba = bv4[0], bb = bv4[1], bc = bv4[2], bd = bv4[3];
        float lora = ta.x * ba.x + ta.y * ba.y + ta.z * ba.z + ta.w * ba.w
                   + tb.x * bb.x + tb.y * bb.y + tb.z * bb.z + tb.w * bb.w
                   + tc.x * bc.x + tc.y * bc.y + tc.z * bc.z + tc.w * bc.w
                   + td.x * bd.x + td.y * bd.y + td.z * bd.z + td.w * bd.w;
        float v = acc[mt][nt][r] + bias[gn] + LORA_SCALING * lora;
        if (DO_GELU) {
          float g = 0.5f * v * (1.0f + erff(v * 0.70710678118654752f));
          size_t dst = ((gm >> 4) * (size_t)(N >> 5) + (gn >> 5)) * 512
                     + (gm & 15) * 8 + (((gn >> 3) & 3) << 7) + (gn & 7);
          ((u16*)outp)[dst] = f2bf(g);
        } else {
          ((float*)outp)[gm * (size_t)N + gn] = v;
        }
      }
    }
  }
}

// ---------- launch ----------
extern "C" void kernel_launch(void* const* d_in, const int* in_sizes, int n_in,
                              void* d_out, int out_size, void* d_ws, size_t ws_size,
                              hipStream_t stream) {
  const float* x    = (const float*)d_in[0];
  const float* W_fc = (const float*)d_in[1];
  const float* b_fc = (const float*)d_in[2];
  const float* A_fc = (const float*)d_in[3];
  const float* B_fc = (const float*)d_in[4];
  const float* W_pr = (const float*)d_in[5];
  const float* b_pr = (const float*)d_in[6];
  const float* A_pr = (const float*)d_in[7];
  const float* B_pr = (const float*)d_in[8];
  float* out = (float*)d_out;

  const int F = in_sizes[2];                 // 4096
  const int D = in_sizes[6];                 // 1024
  const int M = in_sizes[0] / D;             // 8192
  int dsh = 0; while ((1 << dsh) < D) ++dsh;
  int fsh = 0; while ((1 << fsh) < F) ++fsh;

  char* ws = (char*)d_ws;
  unsigned* amax = (unsigned*)ws;
  u16* wq_fc = (u16*)(ws + 1024);
  u16* wq_pr = wq_fc + (size_t)F * D;
  u16* xbf   = wq_pr + (size_t)D * F;
  u16* gbf   = xbf + (size_t)M * D;
  float* t1  = (float*)(gbf + (size_t)M * F);
  float* t2  = t1 + (size_t)M * 16;

  long long wfd4 = (long long)F * D / 4;
  long long wfd8 = (long long)F * D / 8;
  long long xch  = (long long)M * D / 8;

  zero_kernel<<<1, 64, 0, stream>>>(amax);
  absmax2_kernel<<<2048, 256, 0, stream>>>(W_fc, W_pr, wfd4, amax);
  pack_all_kernel<<<2048, 256, 0, stream>>>(W_fc, W_pr, x, amax, wq_fc, wq_pr, xbf,
                                            wfd8, wfd8, xch, dsh - 3, fsh - 3, dsh - 3);
  lora_t_kernel<<<M / 4, 256, 0, stream>>>(xbf, A_fc, t1, D);
  // layer 1: 128x128 tiles -> 2048 blocks (4/CU capacity -> 2 full rounds)
  gemm_qlora_kernel<4, 1><<<dim3((M / 128) * (F / 128)), 256, 0, stream>>>(
      xbf, wq_fc, b_fc, t1, B_fc, (void*)gbf, M, F, D);
  lora_t_kernel<<<M / 4, 256, 0, stream>>>(gbf, A_pr, t2, F);
  // layer 2: 64x128 tiles -> 1024 blocks (fills 4 blocks/CU; 128x128 would give 512)
  gemm_qlora_kernel<2, 0><<<dim3((M / 64) * (D / 128)), 256, 0, stream>>>(
      gbf, wq_pr, b_pr, t2, B_pr, (void*)out, M, D, F);
}

// Round 9
// 1795.099 us; speedup vs baseline: 1.4094x; 1.4094x over previous
//
#include <hip/hip_runtime.h>
#include <hip/hip_bf16.h>
#include <math.h>

typedef unsigned short u16;
typedef __bf16 bf16x8 __attribute__((ext_vector_type(8)));
typedef float floatx4 __attribute__((ext_vector_type(4)));

#define LORA_SCALING 2.0f   // alpha 32 / rank 16

// Frag-major layout for all GEMM operands (1 KB per 16x32 fragment):
// frag idx = (row/16)*(K/32) + (k/32); lane l holds row = 16*(row/16)+(l&15),
// k = 32*(k/32) + (l>>4)*8 .. +7, at frag*512 + l*8 (u16).
// DMA of one frag = linear 1 KB; ds_read at frag_base + lane*16 = MFMA operand.

// ---------- helpers ----------
__device__ __forceinline__ u16 f2bf(float f) {
  unsigned u = __float_as_uint(f);
  u += 0x7fffu + ((u >> 16) & 1u);   // round-to-nearest-even
  return (u16)(u >> 16);
}
__device__ __forceinline__ float bflo(unsigned u) { return __uint_as_float(u << 16); }
__device__ __forceinline__ float bfhi(unsigned u) { return __uint_as_float(u & 0xffff0000u); }

// ---------- zero amax slots (ws poisoned 0xAA each launch) ----------
__global__ void zero_kernel(unsigned* amax) {
  if (threadIdx.x < 2) amax[threadIdx.x] = 0u;
}

// ---------- fused absmax of both weight tensors ----------
__global__ void absmax2_kernel(const float* __restrict__ wa, const float* __restrict__ wb,
                               long long n4, unsigned* __restrict__ out) {
  int which = blockIdx.x & 1;
  const float* w = which ? wb : wa;
  long long i = (long long)(blockIdx.x >> 1) * blockDim.x + threadIdx.x;
  long long stride = (long long)(gridDim.x >> 1) * blockDim.x;
  float m = 0.f;
  for (; i < n4; i += stride) {
    float4 v = ((const float4*)w)[i];
    m = fmaxf(m, fmaxf(fmaxf(fabsf(v.x), fabsf(v.y)), fmaxf(fabsf(v.z), fabsf(v.w))));
  }
#pragma unroll
  for (int o = 32; o > 0; o >>= 1) m = fmaxf(m, __shfl_xor(m, o, 64));
  __shared__ float sm[4];
  int lane = threadIdx.x & 63, wv = threadIdx.x >> 6;
  if (lane == 0) sm[wv] = m;
  __syncthreads();
  if (threadIdx.x == 0) {
    float mm = fmaxf(fmaxf(sm[0], sm[1]), fmaxf(sm[2], sm[3]));
    atomicMax(out + which, __float_as_uint(mm));   // nonneg: uint order == float order
  }
}

// ---------- packing, dst-major: coalesced 16B writes, gathered 32B reads ----------
__device__ __forceinline__ void pack_q(const float* __restrict__ w, u16* __restrict__ dst,
                                       long long d, int nkc, int kc3, float inv, float scale) {
  int l = (int)(d & 63);
  long long frag = d >> 6;
  long long m = (frag / nkc) * 16 + (l & 15);
  long long k8 = (frag % nkc) * 4 + (l >> 4);
  const float4* s = (const float4*)(w + ((m << kc3) + k8) * 8);
  float4 a = s[0], b = s[1];
  union { u16 h[8]; uint4 v; } o;
  o.h[0] = f2bf(fminf(fmaxf(rintf(a.x * inv), -128.f), 127.f) * scale);
  o.h[1] = f2bf(fminf(fmaxf(rintf(a.y * inv), -128.f), 127.f) * scale);
  o.h[2] = f2bf(fminf(fmaxf(rintf(a.z * inv), -128.f), 127.f) * scale);
  o.h[3] = f2bf(fminf(fmaxf(rintf(a.w * inv), -128.f), 127.f) * scale);
  o.h[4] = f2bf(fminf(fmaxf(rintf(b.x * inv), -128.f), 127.f) * scale);
  o.h[5] = f2bf(fminf(fmaxf(rintf(b.y * inv), -128.f), 127.f) * scale);
  o.h[6] = f2bf(fminf(fmaxf(rintf(b.z * inv), -128.f), 127.f) * scale);
  o.h[7] = f2bf(fminf(fmaxf(rintf(b.w * inv), -128.f), 127.f) * scale);
  ((uint4*)dst)[d] = o.v;
}
__device__ __forceinline__ void pack_c(const float* __restrict__ x, u16* __restrict__ dst,
                                       long long d, int nkc, int kc3) {
  int l = (int)(d & 63);
  long long frag = d >> 6;
  long long m = (frag / nkc) * 16 + (l & 15);
  long long k8 = (frag % nkc) * 4 + (l >> 4);
  const float4* s = (const float4*)(x + ((m << kc3) + k8) * 8);
  float4 a = s[0], b = s[1];
  union { u16 h[8]; uint4 v; } o;
  o.h[0] = f2bf(a.x); o.h[1] = f2bf(a.y); o.h[2] = f2bf(a.z); o.h[3] = f2bf(a.w);
  o.h[4] = f2bf(b.x); o.h[5] = f2bf(b.y); o.h[6] = f2bf(b.z); o.h[7] = f2bf(b.w);
  ((uint4*)dst)[d] = o.v;
}

__global__ void pack_all_kernel(const float* __restrict__ wfc, const float* __restrict__ wpr,
                                const float* __restrict__ x, const unsigned* __restrict__ amax,
                                u16* __restrict__ qfc, u16* __restrict__ qpr, u16* __restrict__ xb,
                                long long nfc, long long npr, long long nx, int kfc, int kpr, int kx) {
  float am0 = __uint_as_float(amax[0]);
  float am1 = __uint_as_float(amax[1]);
  float sc0 = am0 * (1.0f / 127.0f), in0 = 127.0f / am0;
  float sc1 = am1 * (1.0f / 127.0f), in1 = 127.0f / am1;
  long long i = (long long)blockIdx.x * blockDim.x + threadIdx.x;
  long long stride = (long long)gridDim.x * blockDim.x;
  long long tot = nfc + npr + nx;
  for (; i < tot; i += stride) {
    if (i < nfc)            pack_q(wfc, qfc, i, 1 << (kfc - 2), kfc, in0, sc0);
    else if (i < nfc + npr) pack_q(wpr, qpr, i - nfc, 1 << (kpr - 2), kpr, in1, sc1);
    else                    pack_c(x, xb, i - nfc - npr, 1 << (kx - 2), kx);
  }
}

// ---------- LoRA t = X(packed bf16) @ A^T(fp32): one wave per row, X read once ----------
__global__ void lora_t_kernel(const u16* __restrict__ X, const float* __restrict__ A,
                              float* __restrict__ T, int K) {
  int wv = threadIdx.x >> 6, lane = threadIdx.x & 63;
  long long row = (long long)blockIdx.x * 4 + wv;
  int nk = K >> 5;
  const u16* xp = X + ((row >> 4) * (long long)nk) * 512 + (row & 15) * 8;
  float acc[16];
#pragma unroll
  for (int r = 0; r < 16; ++r) acc[r] = 0.f;
  int nseg = K >> 3;
  for (int seg = lane; seg < nseg; seg += 64) {
    uint4 xv = *(const uint4*)(xp + (seg >> 2) * 512 + (seg & 3) * 128);
    float x0 = bflo(xv.x), x1 = bfhi(xv.x), x2 = bflo(xv.y), x3 = bfhi(xv.y);
    float x4 = bflo(xv.z), x5 = bfhi(xv.z), x6 = bflo(xv.w), x7 = bfhi(xv.w);
    int k = seg * 8;
#pragma unroll
    for (int r = 0; r < 16; ++r) {
      const float4* ar = (const float4*)(A + (long long)r * K + k);
      float4 a0 = ar[0], a1 = ar[1];
      acc[r] += x0 * a0.x + x1 * a0.y + x2 * a0.z + x3 * a0.w
              + x4 * a1.x + x5 * a1.y + x6 * a1.z + x7 * a1.w;
    }
  }
#pragma unroll
  for (int r = 0; r < 16; ++r) {
    float v = acc[r];
#pragma unroll
    for (int o = 32; o > 0; o >>= 1) v += __shfl_xor(v, o, 64);
    if (lane == r) T[row * 16 + r] = v;
  }
}

// ---------- main GEMM: m97 structure on frag-major layout, K-phase staggered ----------
// Block tile (MT*32) x 128, BK=64 (2 frag-K per iter), 256 threads = 4 waves (2x2);
// wave tile (MT*16) x 64. Single 32/24 KB LDS buffer, plain __syncthreads.
// __launch_bounds__(256,3): cap ~170 regs -> 3 blocks/CU without spilling acc
// (r8: cap 128 -> acc spilled to scratch -> 4.4 GB writes; never cap below acc+frags).
template<int MT, int DO_GELU>
__global__ __launch_bounds__(256, 3)
void gemm_qlora_kernel(const u16* __restrict__ Apk, const u16* __restrict__ Bpk,
                       const float* __restrict__ bias, const float* __restrict__ T,
                       const float* __restrict__ Bl, void* __restrict__ outp,
                       int M, int N, int K) {
  constexpr int AF = 2 * MT;            // A frag-rows per block
  __shared__ u16 sA[AF * 2 * 512];      // [fragrow][ktHalf][512]
  __shared__ u16 sB[8 * 2 * 512];
  const int tid = threadIdx.x;
  const int wave = tid >> 6, lane = tid & 63;
  const int quad = lane >> 4, m16 = lane & 15;

  // XCD partition: id&7 = XCD, bm-local fastest (A strip L2-resident)
  const int bmt = M / (MT * 32);
  const int per = bmt >> 3;
  int xcd = blockIdx.x & 7, t = blockIdx.x >> 3;
  int bm = xcd * per + (t & (per - 1));
  int bn = t / per;

  const int nk32 = K >> 5;              // frag-K count
  const int nkb = K >> 6;               // BK=64 iters (power of 2)
  const int phase = (t * 5) & (nkb - 1);  // stagger: co-resident blocks hit different K-slices

  // staging: A frags s = wave*MT+i -> fragrow s>>1, half s&1 (MT insts/wave)
  //          B frags s = wave*4+i  -> fragrow s>>1, half s&1 (4 insts/wave)
  const u16* gA[MT]; u16* lA[MT];
#pragma unroll
  for (int i = 0; i < MT; ++i) {
    int s = wave * MT + i;
    gA[i] = Apk + ((size_t)(bm * AF + (s >> 1)) * nk32 + (s & 1)) * 512 + lane * 8;
    lA[i] = sA + s * 512;
  }
  const u16* gB[4]; u16* lB[4];
#pragma unroll
  for (int i = 0; i < 4; ++i) {
    int s = wave * 4 + i;
    gB[i] = Bpk + ((size_t)(bn * 8 + (s >> 1)) * nk32 + (s & 1)) * 512 + lane * 8;
    lB[i] = sB + s * 512;
  }

  const int warow = (wave >> 1) * MT;   // this wave's A fragrow base
  const int wbcol = (wave & 1) * 4;     // this wave's B fragrow base
  const u16* rA = sA + warow * 2 * 512 + lane * 8;
  const u16* rB = sB + wbcol * 2 * 512 + lane * 8;

  floatx4 acc[MT][4] = {};

#pragma unroll 1
  for (int ib = 0; ib < nkb; ++ib) {
    int ktb = ib + phase; if (ktb >= nkb) ktb -= nkb;
    size_t o = (size_t)ktb * 1024;      // 2 frag-K per iter * 512
#pragma unroll
    for (int i = 0; i < MT; ++i)
      __builtin_amdgcn_global_load_lds((const __attribute__((address_space(1))) void*)(gA[i] + o),
                                       (__attribute__((address_space(3))) void*)lA[i], 16, 0, 0);
#pragma unroll
    for (int i = 0; i < 4; ++i)
      __builtin_amdgcn_global_load_lds((const __attribute__((address_space(1))) void*)(gB[i] + o),
                                       (__attribute__((address_space(3))) void*)lB[i], 16, 0, 0);
    __syncthreads();

#pragma unroll
    for (int h = 0; h < 2; ++h) {
      bf16x8 av[MT], bv[4];
#pragma unroll
      for (int mt = 0; mt < MT; ++mt) av[mt] = *(const bf16x8*)(rA + (mt * 2 + h) * 512);
#pragma unroll
      for (int nt = 0; nt < 4; ++nt) bv[nt] = *(const bf16x8*)(rB + (nt * 2 + h) * 512);
#pragma unroll
      for (int mt = 0; mt < MT; ++mt)
#pragma unroll
        for (int nt = 0; nt < 4; ++nt)
          acc[mt][nt] = __builtin_amdgcn_mfma_f32_16x16x32_bf16(av[mt], bv[nt], acc[mt][nt], 0, 0, 0);
    }
    __syncthreads();
  }

  // epilogue: C/D layout row=(lane>>4)*4+reg, col=lane&15
  const int wm = (wave >> 1) * (MT * 16), wn = (wave & 1) * 64;
  const float* Trow = T + (size_t)bm * (MT * 32) * 16;
  const float* Blrow = Bl + (size_t)bn * 128 * 16;
#pragma unroll 1
  for (int mt = 0; mt < MT; ++mt) {
#pragma unroll 1
    for (int r = 0; r < 4; ++r) {
      int ml = wm + mt * 16 + quad * 4 + r;
      size_t gm = (size_t)bm * (MT * 32) + ml;
      const float4* tv = (const float4*)(Trow + (size_t)ml * 16);
      float4 ta = tv[0], tb = tv[1], tc = tv[2], td = tv[3];
#pragma unroll
      for (int nt = 0; nt < 4; ++nt) {
        int nl = wn + nt * 16 + m16;
        size_t gn = (size_t)bn * 128 + nl;
        const float4* bv4 = (const float4*)(Blrow + (size_t)nl * 16);
        float4 ba = bv4[0], bb = bv4[1], bc = bv4[2], bd = bv4[3];
        float lora = ta.x * ba.x + ta.y * ba.y + ta.z * ba.z + ta.w * ba.w
                   + tb.x * bb.x + tb.y * bb.y + tb.z * bb.z + tb.w * bb.w
                   + tc.x * bc.x + tc.y * bc.y + tc.z * bc.z + tc.w * bc.w
                   + td.x * bd.x + td.y * bd.y + td.z * bd.z + td.w * bd.w;
        float v = acc[mt][nt][r] + bias[gn] + LORA_SCALING * lora;
        if (DO_GELU) {
          float g = 0.5f * v * (1.0f + erff(v * 0.70710678118654752f));
          size_t dst = ((gm >> 4) * (size_t)(N >> 5) + (gn >> 5)) * 512
                     + (gm & 15) * 8 + (((gn >> 3) & 3) << 7) + (gn & 7);
          ((u16*)outp)[dst] = f2bf(g);
        } else {
          ((float*)outp)[gm * (size_t)N + gn] = v;
        }
      }
    }
  }
}

// ---------- launch ----------
extern "C" void kernel_launch(void* const* d_in, const int* in_sizes, int n_in,
                              void* d_out, int out_size, void* d_ws, size_t ws_size,
                              hipStream_t stream) {
  const float* x    = (const float*)d_in[0];
  const float* W_fc = (const float*)d_in[1];
  const float* b_fc = (const float*)d_in[2];
  const float* A_fc = (const float*)d_in[3];
  const float* B_fc = (const float*)d_in[4];
  const float* W_pr = (const float*)d_in[5];
  const float* b_pr = (const float*)d_in[6];
  const float* A_pr = (const float*)d_in[7];
  const float* B_pr = (const float*)d_in[8];
  float* out = (float*)d_out;

  const int F = in_sizes[2];                 // 4096
  const int D = in_sizes[6];                 // 1024
  const int M = in_sizes[0] / D;             // 8192
  int dsh = 0; while ((1 << dsh) < D) ++dsh;
  int fsh = 0; while ((1 << fsh) < F) ++fsh;

  char* ws = (char*)d_ws;
  unsigned* amax = (unsigned*)ws;
  u16* wq_fc = (u16*)(ws + 1024);
  u16* wq_pr = wq_fc + (size_t)F * D;
  u16* xbf   = wq_pr + (size_t)D * F;
  u16* gbf   = xbf + (size_t)M * D;
  float* t1  = (float*)(gbf + (size_t)M * F);
  float* t2  = t1 + (size_t)M * 16;

  long long wfd4 = (long long)F * D / 4;
  long long wfd8 = (long long)F * D / 8;
  long long xch  = (long long)M * D / 8;

  zero_kernel<<<1, 64, 0, stream>>>(amax);
  absmax2_kernel<<<2048, 256, 0, stream>>>(W_fc, W_pr, wfd4, amax);
  pack_all_kernel<<<2048, 256, 0, stream>>>(W_fc, W_pr, x, amax, wq_fc, wq_pr, xbf,
                                            wfd8, wfd8, xch, dsh - 3, fsh - 3, dsh - 3);
  lora_t_kernel<<<M / 4, 256, 0, stream>>>(xbf, A_fc, t1, D);
  // layer 1: 128x128 tiles -> 2048 blocks
  gemm_qlora_kernel<4, 1><<<dim3((M / 128) * (F / 128)), 256, 0, stream>>>(
      xbf, wq_fc, b_fc, t1, B_fc, (void*)gbf, M, F, D);
  lora_t_kernel<<<M / 4, 256, 0, stream>>>(gbf, A_pr, t2, F);
  // layer 2: 64x128 tiles -> 1024 blocks (fills 3 blocks/CU)
  gemm_qlora_kernel<2, 0><<<dim3((M / 64) * (D / 128)), 256, 0, stream>>>(
      gbf, wq_pr, b_pr, t2, B_pr, (void*)out, M, D, F);
}